// Round 5
// baseline (281.937 us; speedup 1.0000x reference)
//
#include <hip/hip_runtime.h>

static constexpr int BATCH = 16;
static constexpr int NNODE = 4096;
static constexpr int NEDGE = 65536;            // 1 << 16
static constexpr int ROWS  = BATCH * NNODE;    // 65536

typedef _Float16 half8  __attribute__((ext_vector_type(8)));
typedef _Float16 half4v __attribute__((ext_vector_type(4)));
typedef _Float16 half2v __attribute__((ext_vector_type(2)));
typedef float    f32x4  __attribute__((ext_vector_type(4)));
typedef float    f32x2  __attribute__((ext_vector_type(2)));

template<typename T, int N> struct VT;
template<> struct VT<_Float16, 2> { using type = half2v; };
template<> struct VT<_Float16, 4> { using type = half4v; };
template<> struct VT<float, 2>    { using type = f32x2; };
template<> struct VT<float, 4>    { using type = f32x4; };

// ---------------- CSR build (once; reused by all 3 layers) ----------------

__global__ __launch_bounds__(256) void count_kernel(
    const int* __restrict__ ei, const int* __restrict__ mask,
    int* __restrict__ counts)
{
    const int idx = blockIdx.x * 256 + threadIdx.x;
    const int b = idx >> 16;
    const int e = idx & (NEDGE - 1);
    const int* eib = ei + (size_t)b * 2 * NEDGE;
    const int u = eib[e];
    const int v = eib[NEDGE + e];
    const int mrow = b * NNODE;
    if (mask[mrow + u] != 0 && mask[mrow + v] != 0)
        atomicAdd(&counts[mrow + v], 1);
}

__global__ __launch_bounds__(256) void scan_kernel(
    const int* __restrict__ counts, int* __restrict__ row_start,
    int* __restrict__ cursor)
{
    __shared__ int sums[256];
    const int b = blockIdx.x, t = threadIdx.x;
    const int* c = counts + b * NNODE;
    int* rs = row_start + b * (NNODE + 1);
    int* cu = cursor + b * NNODE;

    int local[16]; int s = 0;
    #pragma unroll
    for (int i = 0; i < 16; ++i) { local[i] = c[t * 16 + i]; s += local[i]; }
    sums[t] = s;
    __syncthreads();
    for (int off = 1; off < 256; off <<= 1) {
        int v = (t >= off) ? sums[t - off] : 0;
        __syncthreads();
        sums[t] += v;
        __syncthreads();
    }
    int run = (t == 0) ? 0 : sums[t - 1];
    #pragma unroll
    for (int i = 0; i < 16; ++i) { rs[t * 16 + i] = run; cu[t * 16 + i] = run; run += local[i]; }
    if (t == 255) rs[NNODE] = run;
}

__global__ __launch_bounds__(256) void fill_kernel(
    const int* __restrict__ ei, const float* __restrict__ ew,
    const int* __restrict__ mask, int* __restrict__ cursor,
    unsigned long long* __restrict__ bkt)
{
    const int idx = blockIdx.x * 256 + threadIdx.x;
    const int b = idx >> 16;
    const int e = idx & (NEDGE - 1);
    const int* eib = ei + (size_t)b * 2 * NEDGE;
    const int u = eib[e];
    const int v = eib[NEDGE + e];
    const int mrow = b * NNODE;
    if (mask[mrow + u] != 0 && mask[mrow + v] != 0) {
        const float w = ew[(size_t)b * NEDGE + e];
        const int pos = atomicAdd(&cursor[mrow + v], 1);
        bkt[(size_t)b * NEDGE + pos] =
            ((unsigned long long)__float_as_uint(w) << 32) | (unsigned)u;
    }
}

// W [K][Nd] fp32 -> Wt [Nd][K] fp16
__global__ __launch_bounds__(256) void wt_kernel(
    const float* __restrict__ W, _Float16* __restrict__ Wt, int K, int Nd)
{
    int i = blockIdx.x * 256 + threadIdx.x;
    if (i < K * Nd) {
        int k = i / Nd, n = i - k * Nd;
        Wt[n * K + k] = (_Float16)W[i];
    }
}

// ---------------- H = X @ Wt^T (fp16 in, fp32 acc, fp16 out) ----------------
// 128x128 tile, BK=32, 4 waves of 64x64, mfma_f32_16x16x32_f16 with
// OPERAND-SWAPPED call: D = Wt_frag * X_frag so each lane holds
// (m = l15, n = quad*4 + r) -> 4 consecutive output cols = one 8B store.
// Optional fused epilogue: relu(acc + bias[n]) * (mask[row]!=0).
template<int K, bool EPI>
__global__ __launch_bounds__(256) void gemm_mfma(
    const _Float16* __restrict__ X,   // [M, K]
    const _Float16* __restrict__ Wt,  // [Nd, K]
    _Float16* __restrict__ H,         // [M, Nd]
    int Nd, const float* __restrict__ bias, const int* __restrict__ mask)
{
    __shared__ _Float16 As[128 * 32];   // [m][k] row-major
    __shared__ _Float16 Bs[128 * 32];   // [n][k] row-major

    const int tid  = threadIdx.x;
    const int lane = tid & 63;
    const int wave = tid >> 6;
    const int wr = wave >> 1, wc = wave & 1;
    const int quad = lane >> 4;
    const int l15  = lane & 15;

    const size_t bm = (size_t)blockIdx.y * 128;
    const int    bn = blockIdx.x * 128;

    f32x4 acc[4][4] = {};

    const int sr = tid >> 2;
    const int sc = (tid & 3) * 8;
    const _Float16* Ag0 = X  + (bm + sr) * K + sc;
    const _Float16* Ag1 = X  + (bm + 64 + sr) * K + sc;
    const _Float16* Bg0 = Wt + (size_t)(bn + sr) * K + sc;
    const _Float16* Bg1 = Wt + (size_t)(bn + 64 + sr) * K + sc;

    const _Float16* ap = As + (wr * 64 + l15) * 32 + quad * 8;
    const _Float16* bp = Bs + (wc * 64 + l15) * 32 + quad * 8;

    for (int k0 = 0; k0 < K; k0 += 32) {
        __builtin_amdgcn_global_load_lds(
            (const __attribute__((address_space(1))) void*)(Ag0 + k0),
            (__attribute__((address_space(3))) void*)(As + tid * 8), 16, 0, 0);
        __builtin_amdgcn_global_load_lds(
            (const __attribute__((address_space(1))) void*)(Ag1 + k0),
            (__attribute__((address_space(3))) void*)(As + 2048 + tid * 8), 16, 0, 0);
        __builtin_amdgcn_global_load_lds(
            (const __attribute__((address_space(1))) void*)(Bg0 + k0),
            (__attribute__((address_space(3))) void*)(Bs + tid * 8), 16, 0, 0);
        __builtin_amdgcn_global_load_lds(
            (const __attribute__((address_space(1))) void*)(Bg1 + k0),
            (__attribute__((address_space(3))) void*)(Bs + 2048 + tid * 8), 16, 0, 0);
        __syncthreads();

        half8 af[4], bf[4];
        #pragma unroll
        for (int mi = 0; mi < 4; ++mi) af[mi] = *(const half8*)(ap + mi * 16 * 32);
        #pragma unroll
        for (int ni = 0; ni < 4; ++ni) bf[ni] = *(const half8*)(bp + ni * 16 * 32);

        #pragma unroll
        for (int mi = 0; mi < 4; ++mi)
            #pragma unroll
            for (int ni = 0; ni < 4; ++ni)
                acc[mi][ni] = __builtin_amdgcn_mfma_f32_16x16x32_f16(
                    bf[ni], af[mi], acc[mi][ni], 0, 0, 0);   // swapped!
        __syncthreads();
    }

    // lane holds (row = bm + wr*64 + mi*16 + l15, cols = bn + wc*64 + ni*16 + quad*4 .. +3)
    #pragma unroll
    for (int mi = 0; mi < 4; ++mi) {
        const size_t row = bm + wr * 64 + mi * 16 + l15;
        bool ok = true;
        if constexpr (EPI) ok = (mask[row] != 0);
        #pragma unroll
        for (int ni = 0; ni < 4; ++ni) {
            const int n = bn + wc * 64 + ni * 16 + quad * 4;
            f32x4 v = acc[mi][ni];
            half4v o;
            if constexpr (EPI) {
                #pragma unroll
                for (int r = 0; r < 4; ++r)
                    o[r] = (_Float16)(ok ? fmaxf(v[r] + bias[n + r], 0.0f) : 0.0f);
            } else {
                #pragma unroll
                for (int r = 0; r < 4; ++r) o[r] = (_Float16)v[r];
            }
            *(half4v*)&H[row * Nd + n] = o;
        }
    }
}

// ---------------- gather: agg[v] = sum_e w * H[u]  (one wave per node) ------
// 8-deep MLP unroll; batch-to-XCD swizzle (b = blockIdx.x & 15) so each
// batch's H slab stays in one XCD's L2. Optional epilogue relu(acc+b)*mask.
template<int D, bool EPI, typename IT, typename OT>
__global__ __launch_bounds__(256) void gather_kernel(
    const int* __restrict__ row_start, const unsigned long long* __restrict__ bkt,
    const IT* __restrict__ H, const int* __restrict__ mask,
    const float* __restrict__ bias, OT* __restrict__ OUT)
{
    constexpr int PER = D / 64;
    using ivec = typename VT<IT, PER>::type;
    using ovec = typename VT<OT, PER>::type;

    const int bx   = blockIdx.x;
    const int b    = bx & 15;                          // XCD-affine batch
    const int node = ((bx >> 4) << 2) | (threadIdx.x >> 6);
    const int lane = threadIdx.x & 63;
    const int mrow = b * NNODE + node;

    const int* rs = row_start + b * (NNODE + 1);
    const int s = rs[node], e = rs[node + 1];

    float acc[PER] = {};
    const unsigned long long* bk = bkt + (size_t)b * NEDGE;
    const IT* Hb = H + (size_t)b * NNODE * D + lane * PER;

    for (int i = s; i < e; i += 8) {
        const int cnt = e - i;   // >= 1
        unsigned long long pk[8];
        #pragma unroll
        for (int j = 0; j < 8; ++j) pk[j] = bk[i + j];   // slack-safe over-read

        const int u0 = (int)(pk[0] & 0xffffffffu);
        float wj[8];
        const IT* hp[8];
        #pragma unroll
        for (int j = 0; j < 8; ++j) {
            const bool okj = (j < cnt);
            const int u = okj ? (int)(pk[j] & 0xffffffffu) : u0;
            wj[j] = okj ? __uint_as_float((unsigned)(pk[j] >> 32)) : 0.0f;
            hp[j] = Hb + (size_t)u * D;
        }
        ivec hv[8];
        #pragma unroll
        for (int j = 0; j < 8; ++j) hv[j] = *(const ivec*)hp[j];
        #pragma unroll
        for (int j = 0; j < 8; ++j)
            #pragma unroll
            for (int c = 0; c < PER; ++c) acc[c] += wj[j] * (float)hv[j][c];
    }

    if constexpr (EPI) {
        if (mask[mrow] != 0) {
            #pragma unroll
            for (int c = 0; c < PER; ++c)
                acc[c] = fmaxf(acc[c] + bias[lane * PER + c], 0.0f);
        } else {
            #pragma unroll
            for (int c = 0; c < PER; ++c) acc[c] = 0.0f;
        }
    }

    ovec o;
    #pragma unroll
    for (int c = 0; c < PER; ++c) o[c] = (OT)acc[c];
    *(ovec*)(OUT + (size_t)mrow * D + lane * PER) = o;
}

extern "C" void kernel_launch(void* const* d_in, const int* in_sizes, int n_in,
                              void* d_out, int out_size, void* d_ws, size_t ws_size,
                              hipStream_t stream) {
    const float* x    = (const float*)d_in[0];
    const int*   ei   = (const int*)  d_in[1];
    const float* ew   = (const float*)d_in[2];
    const int*   mask = (const int*)  d_in[3];
    const float* W1   = (const float*)d_in[4];
    const float* b1   = (const float*)d_in[5];
    const float* W2   = (const float*)d_in[6];
    const float* b2   = (const float*)d_in[7];
    const float* W3   = (const float*)d_in[8];
    const float* b3   = (const float*)d_in[9];
    float* out = (float*)d_out;

    // Workspace layout (~137 MB of the 256 MiB ws):
    char* ws = (char*)d_ws;
    _Float16* A1 = (_Float16*)(ws);                                   // 16 MB  [65536x128]
    _Float16* O1 = (_Float16*)(ws + (16u  << 20));                    // 32 MB  [65536x256]
    _Float16* A2 = (_Float16*)(ws + (48u  << 20));                    // 32 MB  [65536x256]
    _Float16* O2 = (_Float16*)(ws + (80u  << 20));                    // 32 MB  [65536x256]
    _Float16* H3 = (_Float16*)(ws + (112u << 20));                    // 16 MB  [65536x128]
    unsigned long long* bkt = (unsigned long long*)(ws + (128u << 20)); // 8 MB
    _Float16* Wt1  = (_Float16*)(ws + (136u << 20));                  // 64 KB  [256][128]
    _Float16* Wt2  = Wt1 + 128 * 256;                                 // 128 KB [256][256]
    _Float16* Wt3  = Wt2 + 256 * 256;                                 // 64 KB  [128][256]
    int* counts    = (int*)(Wt3 + 256 * 128);
    int* row_start = counts + BATCH * NNODE;
    int* cursor    = row_start + BATCH * (NNODE + 1);

    const dim3 blk(256);
    const int edgeBlocks   = BATCH * NEDGE / 256;   // 4096
    const int gatherBlocks = ROWS / 4;              // 16384

    // ---- CSR build (layer-invariant) ----
    hipMemsetAsync(counts, 0, (size_t)BATCH * NNODE * sizeof(int), stream);
    count_kernel<<<edgeBlocks, blk, 0, stream>>>(ei, mask, counts);
    scan_kernel<<<BATCH, blk, 0, stream>>>(counts, row_start, cursor);
    fill_kernel<<<edgeBlocks, blk, 0, stream>>>(ei, ew, mask, cursor, bkt);

    // ---- weight transpose+cast ----
    wt_kernel<<<(128 * 256 + 255) / 256, blk, 0, stream>>>(W1, Wt1, 128, 256);
    wt_kernel<<<(256 * 256 + 255) / 256, blk, 0, stream>>>(W2, Wt2, 256, 256);
    wt_kernel<<<(256 * 128 + 255) / 256, blk, 0, stream>>>(W3, Wt3, 256, 128);

    // ---- Layer 1 (aggregate-first): A1 = gatherW(x) [128d fp32->fp16];
    //      O1 = relu(A1 @ W1 + b1) * mask  [256d]
    gather_kernel<128, false, float, _Float16><<<gatherBlocks, blk, 0, stream>>>(
        row_start, bkt, x, mask, b1, A1);
    gemm_mfma<128, true><<<dim3(2, ROWS / 128), blk, 0, stream>>>(
        A1, Wt1, O1, 256, b1, mask);

    // ---- Layer 2 (aggregate-first): A2 = gatherW(O1) [256d];
    //      O2 = relu(A2 @ W2 + b2) * mask  [256d]
    gather_kernel<256, false, _Float16, _Float16><<<gatherBlocks, blk, 0, stream>>>(
        row_start, bkt, O1, mask, b2, A2);
    gemm_mfma<256, true><<<dim3(2, ROWS / 128), blk, 0, stream>>>(
        A2, Wt2, O2, 256, b2, mask);

    // ---- Layer 3 (transform-first): H3 = O2 @ W3 [128d];
    //      out = relu(gatherW(H3) + b3) * mask  [128d fp32]
    gemm_mfma<256, false><<<dim3(1, ROWS / 128), blk, 0, stream>>>(
        O2, Wt3, H3, 128, b3, mask);
    gather_kernel<128, true, _Float16, float><<<gatherBlocks, blk, 0, stream>>>(
        row_start, bkt, H3, mask, b3, out);
}

// Round 7
// 276.935 us; speedup vs baseline: 1.0181x; 1.0181x over previous
//
#include <hip/hip_runtime.h>

static constexpr int BATCH = 16;
static constexpr int NNODE = 4096;
static constexpr int NEDGE = 65536;            // 1 << 16
static constexpr int ROWS  = BATCH * NNODE;    // 65536

typedef _Float16 half8  __attribute__((ext_vector_type(8)));
typedef _Float16 half4v __attribute__((ext_vector_type(4)));
typedef _Float16 half2v __attribute__((ext_vector_type(2)));
typedef float    f32x4  __attribute__((ext_vector_type(4)));
typedef float    f32x2  __attribute__((ext_vector_type(2)));

template<typename T, int N> struct VT;
template<> struct VT<_Float16, 2> { using type = half2v; };
template<> struct VT<_Float16, 4> { using type = half4v; };
template<> struct VT<float, 2>    { using type = f32x2; };
template<> struct VT<float, 4>    { using type = f32x4; };

// ---------------- CSR build (once; reused by all 3 layers) ----------------

__global__ __launch_bounds__(256) void count_kernel(
    const int* __restrict__ ei, const int* __restrict__ mask,
    int* __restrict__ counts)
{
    const int idx = blockIdx.x * 256 + threadIdx.x;
    const int b = idx >> 16;
    const int e = idx & (NEDGE - 1);
    const int* eib = ei + (size_t)b * 2 * NEDGE;
    const int u = eib[e];
    const int v = eib[NEDGE + e];
    const int mrow = b * NNODE;
    if (mask[mrow + u] != 0 && mask[mrow + v] != 0)
        atomicAdd(&counts[mrow + v], 1);
}

__global__ __launch_bounds__(256) void scan_kernel(
    const int* __restrict__ counts, int* __restrict__ row_start,
    int* __restrict__ cursor)
{
    __shared__ int sums[256];
    const int b = blockIdx.x, t = threadIdx.x;
    const int* c = counts + b * NNODE;
    int* rs = row_start + b * (NNODE + 1);
    int* cu = cursor + b * NNODE;

    int local[16]; int s = 0;
    #pragma unroll
    for (int i = 0; i < 16; ++i) { local[i] = c[t * 16 + i]; s += local[i]; }
    sums[t] = s;
    __syncthreads();
    for (int off = 1; off < 256; off <<= 1) {
        int v = (t >= off) ? sums[t - off] : 0;
        __syncthreads();
        sums[t] += v;
        __syncthreads();
    }
    int run = (t == 0) ? 0 : sums[t - 1];
    #pragma unroll
    for (int i = 0; i < 16; ++i) { rs[t * 16 + i] = run; cu[t * 16 + i] = run; run += local[i]; }
    if (t == 255) rs[NNODE] = run;
}

// bkt[b][pos] = (fp16bits(w) << 16) | u   (u < 4096 fits easily)
__global__ __launch_bounds__(256) void fill_kernel(
    const int* __restrict__ ei, const float* __restrict__ ew,
    const int* __restrict__ mask, int* __restrict__ cursor,
    unsigned int* __restrict__ bkt)
{
    const int idx = blockIdx.x * 256 + threadIdx.x;
    const int b = idx >> 16;
    const int e = idx & (NEDGE - 1);
    const int* eib = ei + (size_t)b * 2 * NEDGE;
    const int u = eib[e];
    const int v = eib[NEDGE + e];
    const int mrow = b * NNODE;
    if (mask[mrow + u] != 0 && mask[mrow + v] != 0) {
        const _Float16 w = (_Float16)ew[(size_t)b * NEDGE + e];
        const unsigned short wb = __builtin_bit_cast(unsigned short, w);
        const int pos = atomicAdd(&cursor[mrow + v], 1);
        bkt[(size_t)b * NEDGE + pos] = ((unsigned)wb << 16) | (unsigned)u;
    }
}

// W [K][Nd] fp32 -> Wt [Nd][K] fp16
__global__ __launch_bounds__(256) void wt_kernel(
    const float* __restrict__ W, _Float16* __restrict__ Wt, int K, int Nd)
{
    int i = blockIdx.x * 256 + threadIdx.x;
    if (i < K * Nd) {
        int k = i / Nd, n = i - k * Nd;
        Wt[n * K + k] = (_Float16)W[i];
    }
}

// ---------------- H = X @ Wt^T (fp16 in, fp32 acc, fp16 out) ----------------
// 128x128 tile, BK=32, 4 waves of 64x64, operand-swapped mfma so each lane
// holds 4 consecutive output cols. Epilogue restages through padded LDS
// (stride 72 halfs) for fully-coalesced 16B stores; each lane reads TWO
// half8 chunks (full 16x64 coverage: 16 rows x 8 chunks = 64 lanes x 2).
template<int K, bool EPI>
__global__ __launch_bounds__(256) void gemm_mfma(
    const _Float16* __restrict__ X,   // [M, K]
    const _Float16* __restrict__ Wt,  // [Nd, K]
    _Float16* __restrict__ H,         // [M, Nd]
    int Nd, const float* __restrict__ bias, const int* __restrict__ mask)
{
    __shared__ _Float16 As[128 * 32];     // [m][k]
    __shared__ _Float16 Bs[128 * 32];     // [n][k]
    __shared__ _Float16 stg_all[4 * 16 * 72];  // per-wave 16x64 (+8 pad) restage

    const int tid  = threadIdx.x;
    const int lane = tid & 63;
    const int wave = tid >> 6;
    const int wr = wave >> 1, wc = wave & 1;
    const int quad = lane >> 4;
    const int l15  = lane & 15;

    const size_t bm = (size_t)blockIdx.y * 128;
    const int    bn = blockIdx.x * 128;

    f32x4 acc[4][4] = {};

    const int sr = tid >> 2;
    const int sc = (tid & 3) * 8;
    const _Float16* Ag0 = X  + (bm + sr) * K + sc;
    const _Float16* Ag1 = X  + (bm + 64 + sr) * K + sc;
    const _Float16* Bg0 = Wt + (size_t)(bn + sr) * K + sc;
    const _Float16* Bg1 = Wt + (size_t)(bn + 64 + sr) * K + sc;

    const _Float16* ap = As + (wr * 64 + l15) * 32 + quad * 8;
    const _Float16* bp = Bs + (wc * 64 + l15) * 32 + quad * 8;

    for (int k0 = 0; k0 < K; k0 += 32) {
        __builtin_amdgcn_global_load_lds(
            (const __attribute__((address_space(1))) void*)(Ag0 + k0),
            (__attribute__((address_space(3))) void*)(As + tid * 8), 16, 0, 0);
        __builtin_amdgcn_global_load_lds(
            (const __attribute__((address_space(1))) void*)(Ag1 + k0),
            (__attribute__((address_space(3))) void*)(As + 2048 + tid * 8), 16, 0, 0);
        __builtin_amdgcn_global_load_lds(
            (const __attribute__((address_space(1))) void*)(Bg0 + k0),
            (__attribute__((address_space(3))) void*)(Bs + tid * 8), 16, 0, 0);
        __builtin_amdgcn_global_load_lds(
            (const __attribute__((address_space(1))) void*)(Bg1 + k0),
            (__attribute__((address_space(3))) void*)(Bs + 2048 + tid * 8), 16, 0, 0);
        __syncthreads();

        half8 af[4], bf[4];
        #pragma unroll
        for (int mi = 0; mi < 4; ++mi) af[mi] = *(const half8*)(ap + mi * 16 * 32);
        #pragma unroll
        for (int ni = 0; ni < 4; ++ni) bf[ni] = *(const half8*)(bp + ni * 16 * 32);

        #pragma unroll
        for (int mi = 0; mi < 4; ++mi)
            #pragma unroll
            for (int ni = 0; ni < 4; ++ni)
                acc[mi][ni] = __builtin_amdgcn_mfma_f32_16x16x32_f16(
                    bf[ni], af[mi], acc[mi][ni], 0, 0, 0);   // swapped
        __syncthreads();
    }

    // Epilogue: lane holds rows (l15) x cols (ni*16+quad*4..+3) of the wave's
    // 64x64 tile. Stage 16x64 slices in LDS, read back coalesced, 2x16B/lane.
    _Float16* stg = stg_all + wave * 16 * 72;
    const int rr = lane >> 2;            // readback row (0..15)
    const int cc = (lane & 3) * 8;       // readback col chunks: cc and cc+32
    #pragma unroll
    for (int mi = 0; mi < 4; ++mi) {
        const size_t row = bm + wr * 64 + mi * 16 + l15;
        bool ok = true;
        if constexpr (EPI) ok = (mask[row] != 0);
        #pragma unroll
        for (int ni = 0; ni < 4; ++ni) {
            const int n = bn + wc * 64 + ni * 16 + quad * 4;
            f32x4 v = acc[mi][ni];
            half4v o;
            if constexpr (EPI) {
                #pragma unroll
                for (int r = 0; r < 4; ++r)
                    o[r] = (_Float16)(ok ? fmaxf(v[r] + bias[n + r], 0.0f) : 0.0f);
            } else {
                #pragma unroll
                for (int r = 0; r < 4; ++r) o[r] = (_Float16)v[r];
            }
            *(half4v*)&stg[l15 * 72 + ni * 16 + quad * 4] = o;
        }
        // wave-internal ds_write -> ds_read; compiler inserts lgkmcnt waits
        half8 v0 = *(const half8*)&stg[rr * 72 + cc];
        half8 v1 = *(const half8*)&stg[rr * 72 + cc + 32];
        const size_t grow = bm + wr * 64 + mi * 16 + rr;
        _Float16* hp = &H[grow * Nd + bn + wc * 64];
        *(half8*)(hp + cc)      = v0;
        *(half8*)(hp + cc + 32) = v1;
    }
}

// ---------------- gather: agg[v] = sum_e w * H[u] ----------------
// One wave per TWO nodes (independent edge lists, chunk-4 each -> ~8
// independent row loads in flight). Linear block->node mapping.
template<int D, bool EPI, typename IT, typename OT>
__global__ __launch_bounds__(256) void gather_kernel(
    const int* __restrict__ row_start, const unsigned int* __restrict__ bkt,
    const IT* __restrict__ H, const int* __restrict__ mask,
    const float* __restrict__ bias, OT* __restrict__ OUT)
{
    constexpr int PER = D / 64;
    using ivec = typename VT<IT, PER>::type;
    using ovec = typename VT<OT, PER>::type;

    const int gw   = blockIdx.x * 4 + (threadIdx.x >> 6);   // [0, ROWS/2)
    const int lane = threadIdx.x & 63;
    const int b    = gw >> 11;            // 2048 node-pairs per batch
    const int n0   = (gw & 2047) * 2;     // nodes n0, n0+1

    const int* rs = row_start + b * (NNODE + 1);
    const int s0 = rs[n0], s1 = rs[n0 + 1], e1 = rs[n0 + 2];
    const int len0 = s1 - s0, len1 = e1 - s1;

    float acc0[PER] = {}, acc1[PER] = {};
    const unsigned* bk = bkt + (size_t)b * NEDGE;
    const IT* Hb = H + (size_t)b * NNODE * D + lane * PER;

    const int lmax = len0 > len1 ? len0 : len1;
    const int iters = (lmax + 3) >> 2;
    for (int it = 0; it < iters; ++it) {
        const int i0 = s0 + it * 4, i1 = s1 + it * 4;
        unsigned pk0[4], pk1[4];
        #pragma unroll
        for (int j = 0; j < 4; ++j) { pk0[j] = bk[i0 + j]; pk1[j] = bk[i1 + j]; }

        float w0[4], w1[4];
        const IT *hp0[4], *hp1[4];
        #pragma unroll
        for (int j = 0; j < 4; ++j) {
            const bool ok0 = (i0 + j < s1), ok1 = (i1 + j < e1);
            const unsigned u0 = ok0 ? (pk0[j] & 0xffffu) : 0u;
            const unsigned u1 = ok1 ? (pk1[j] & 0xffffu) : 0u;
            w0[j] = ok0 ? (float)__builtin_bit_cast(_Float16, (unsigned short)(pk0[j] >> 16)) : 0.0f;
            w1[j] = ok1 ? (float)__builtin_bit_cast(_Float16, (unsigned short)(pk1[j] >> 16)) : 0.0f;
            hp0[j] = Hb + (size_t)u0 * D;
            hp1[j] = Hb + (size_t)u1 * D;
        }
        ivec hv0[4], hv1[4];
        #pragma unroll
        for (int j = 0; j < 4; ++j) { hv0[j] = *(const ivec*)hp0[j]; hv1[j] = *(const ivec*)hp1[j]; }
        #pragma unroll
        for (int j = 0; j < 4; ++j)
            #pragma unroll
            for (int c = 0; c < PER; ++c) {
                acc0[c] += w0[j] * (float)hv0[j][c];
                acc1[c] += w1[j] * (float)hv1[j][c];
            }
    }

    if constexpr (EPI) {
        const bool m0 = mask[b * NNODE + n0] != 0;
        const bool m1 = mask[b * NNODE + n0 + 1] != 0;
        #pragma unroll
        for (int c = 0; c < PER; ++c) {
            const float bb = bias[lane * PER + c];
            acc0[c] = m0 ? fmaxf(acc0[c] + bb, 0.0f) : 0.0f;
            acc1[c] = m1 ? fmaxf(acc1[c] + bb, 0.0f) : 0.0f;
        }
    }

    ovec o0, o1;
    #pragma unroll
    for (int c = 0; c < PER; ++c) { o0[c] = (OT)acc0[c]; o1[c] = (OT)acc1[c]; }
    OT* op = OUT + ((size_t)b * NNODE + n0) * D + lane * PER;
    *(ovec*)op = o0;
    *(ovec*)(op + D) = o1;
}

extern "C" void kernel_launch(void* const* d_in, const int* in_sizes, int n_in,
                              void* d_out, int out_size, void* d_ws, size_t ws_size,
                              hipStream_t stream) {
    const float* x    = (const float*)d_in[0];
    const int*   ei   = (const int*)  d_in[1];
    const float* ew   = (const float*)d_in[2];
    const int*   mask = (const int*)  d_in[3];
    const float* W1   = (const float*)d_in[4];
    const float* b1   = (const float*)d_in[5];
    const float* W2   = (const float*)d_in[6];
    const float* b2   = (const float*)d_in[7];
    const float* W3   = (const float*)d_in[8];
    const float* b3   = (const float*)d_in[9];
    float* out = (float*)d_out;

    // Workspace layout:
    char* ws = (char*)d_ws;
    _Float16* A1 = (_Float16*)(ws);                                     // 16 MB [65536x128]
    _Float16* O1 = (_Float16*)(ws + (16u  << 20));                      // 32 MB [65536x256]
    _Float16* A2 = (_Float16*)(ws + (48u  << 20));                      // 32 MB [65536x256]
    _Float16* O2 = (_Float16*)(ws + (80u  << 20));                      // 32 MB [65536x256]
    _Float16* H3 = (_Float16*)(ws + (112u << 20));                      // 16 MB [65536x128]
    unsigned int* bkt = (unsigned int*)(ws + (128u << 20));             // 4 MB
    _Float16* Wt1  = (_Float16*)(ws + (132u << 20));
    _Float16* Wt2  = Wt1 + 128 * 256;
    _Float16* Wt3  = Wt2 + 256 * 256;
    int* counts    = (int*)(Wt3 + 256 * 128);
    int* row_start = counts + BATCH * NNODE;
    int* cursor    = row_start + BATCH * (NNODE + 1);

    const dim3 blk(256);
    const int edgeBlocks   = BATCH * NEDGE / 256;   // 4096
    const int gatherBlocks = ROWS / 8;              // 8192 (2 nodes/wave, 4 waves/blk)

    // ---- CSR build (layer-invariant) ----
    hipMemsetAsync(counts, 0, (size_t)BATCH * NNODE * sizeof(int), stream);
    count_kernel<<<edgeBlocks, blk, 0, stream>>>(ei, mask, counts);
    scan_kernel<<<BATCH, blk, 0, stream>>>(counts, row_start, cursor);
    fill_kernel<<<edgeBlocks, blk, 0, stream>>>(ei, ew, mask, cursor, bkt);

    // ---- weight transpose+cast ----
    wt_kernel<<<(128 * 256 + 255) / 256, blk, 0, stream>>>(W1, Wt1, 128, 256);
    wt_kernel<<<(256 * 256 + 255) / 256, blk, 0, stream>>>(W2, Wt2, 256, 256);
    wt_kernel<<<(256 * 128 + 255) / 256, blk, 0, stream>>>(W3, Wt3, 256, 128);

    // ---- Layer 1 (aggregate-first): A1 = gatherW(x); O1 = relu(A1@W1+b1)*mask
    gather_kernel<128, false, float, _Float16><<<gatherBlocks, blk, 0, stream>>>(
        row_start, bkt, x, mask, b1, A1);
    gemm_mfma<128, true><<<dim3(2, ROWS / 128), blk, 0, stream>>>(
        A1, Wt1, O1, 256, b1, mask);

    // ---- Layer 2 (aggregate-first): A2 = gatherW(O1); O2 = relu(A2@W2+b2)*mask
    gather_kernel<256, false, _Float16, _Float16><<<gatherBlocks, blk, 0, stream>>>(
        row_start, bkt, O1, mask, b2, A2);
    gemm_mfma<256, true><<<dim3(2, ROWS / 128), blk, 0, stream>>>(
        A2, Wt2, O2, 256, b2, mask);

    // ---- Layer 3 (transform-first): H3 = O2@W3; out = relu(gatherW(H3)+b3)*mask
    gemm_mfma<256, false><<<dim3(1, ROWS / 128), blk, 0, stream>>>(
        O2, Wt3, H3, 128, b3, mask);
    gather_kernel<128, true, _Float16, float><<<gatherBlocks, blk, 0, stream>>>(
        row_start, bkt, H3, mask, b3, out);
}